// Round 1
// baseline (123.335 us; speedup 1.0000x reference)
//
#include <hip/hip_runtime.h>
#include <hip/hip_bf16.h>

#define IN_DIMS  8192
#define OUT_DIMS 8192
#define NLAB     63
#define KS       8                    // split-K factor
#define KCH      (IN_DIMS / KS)       // 1024 K per workgroup

typedef short  s16x8 __attribute__((ext_vector_type(8)));
typedef float  f32x4 __attribute__((ext_vector_type(4)));

// ---- bf16 RNE pack: two f32 -> one u32 holding 2 bf16 (lo=a, hi=b) ----
__device__ __forceinline__ unsigned int rne2(float a, float b) {
    unsigned int ua = __float_as_uint(a), ub = __float_as_uint(b);
    ua += 0x7FFFu + ((ua >> 16) & 1u);
    ub += 0x7FFFu + ((ub >> 16) & 1u);
    return (ua >> 16) | (ub & 0xFFFF0000u);
}

__device__ __forceinline__ s16x8 cvt8(float4 a, float4 b) {
    uint4 p;
    p.x = rne2(a.x, a.y); p.y = rne2(a.z, a.w);
    p.z = rne2(b.x, b.y); p.w = rne2(b.z, b.w);
    return __builtin_bit_cast(s16x8, p);
}

// ---- kernel 1: Label f32 (63x8192) -> bf16 A (64x8192, row 63 zero) ----
__global__ __launch_bounds__(256) void k_prep(const float* __restrict__ L,
                                              unsigned short* __restrict__ A) {
    int e0 = (blockIdx.x * 256 + threadIdx.x) * 4;
    if (e0 >= 64 * IN_DIMS) return;
    float4 v = make_float4(0.f, 0.f, 0.f, 0.f);
    if (e0 < NLAB * IN_DIMS) v = *(const float4*)(L + e0);
    uint2 o;
    o.x = rne2(v.x, v.y);
    o.y = rne2(v.z, v.w);
    *(uint2*)(A + e0) = o;
}

// ---- kernel 2: split-K MFMA GEMM  Xp(64x8192) += A(64xK) * W(NxK)^T ----
// LDS-free: A-frags from global bf16 (L2-resident 1MB), W-frags streamed
// f32 from HBM and converted in-register. Partials via f32 atomicAdd.
__global__ __launch_bounds__(256, 4) void k_gemm(const float* __restrict__ W,
                                                 const unsigned short* __restrict__ A,
                                                 float* __restrict__ Xp) {
    const int nblk = blockIdx.x & 127;   // N tile (64 cols)
    const int kspl = blockIdx.x >> 7;    // K split
    const int wave = threadIdx.x >> 6;
    const int lane = threadIdx.x & 63;
    const int r = lane & 15;             // row-in-16 (A:m, W:n), frag layout
    const int g = lane >> 4;             // k-group (8 elems each)

    const int n0    = nblk * 64 + wave * 16;
    const int kbase = kspl * KCH + g * 8;

    const float*          wp = W + (long)(n0 + r) * IN_DIMS + kbase;
    const unsigned short* ap = A + (long)r * IN_DIMS + kbase;

    f32x4 acc[4] = {f32x4{0.f,0.f,0.f,0.f}, f32x4{0.f,0.f,0.f,0.f},
                    f32x4{0.f,0.f,0.f,0.f}, f32x4{0.f,0.f,0.f,0.f}};

    #pragma unroll 2
    for (int kk = 0; kk < KCH; kk += 32) {
        float4 w0 = *(const float4*)(wp + kk);
        float4 w1 = *(const float4*)(wp + kk + 4);
        s16x8 bw = cvt8(w0, w1);             // B-frag: B[k][n], n = n0+r
        #pragma unroll
        for (int t = 0; t < 4; ++t) {        // 4 M-fragments (rows t*16..+15)
            s16x8 av = *(const s16x8*)(ap + (long)t * 16 * IN_DIMS + kk);
            acc[t] = __builtin_amdgcn_mfma_f32_16x16x32_bf16(av, bw, acc[t], 0, 0, 0);
        }
    }

    // D layout: lane holds D[m = t*16 + g*4 + q][n = n0 + r]
    #pragma unroll
    for (int t = 0; t < 4; ++t) {
        #pragma unroll
        for (int q = 0; q < 4; ++q) {
            int m = t * 16 + g * 4 + q;
            atomicAdd(&Xp[(long)m * OUT_DIMS + n0 + r], acc[t][q]);
        }
    }
}

// ---- kernel 3: out(63x8192) = S(63x63) @ relu(X + b).reshape(8192,63)^T ----
__global__ __launch_bounds__(256) void k_out(const float* __restrict__ Xp,
                                             const float* __restrict__ S,
                                             const float* __restrict__ b,
                                             float* __restrict__ out) {
    __shared__ float sS[NLAB * NLAB];    // 63x63
    __shared__ float sml[64 * NLAB];     // 64 output-columns worth of ML rows
    const int k0 = blockIdx.x * 64;

    for (int p = threadIdx.x; p < NLAB * NLAB; p += 256) sS[p] = S[p];
    for (int p = threadIdx.x; p < 64 * NLAB; p += 256) {
        int gi = k0 * NLAB + p;          // flat index into X (row-major 63x8192)
        float v = Xp[gi] + b[gi & (OUT_DIMS - 1)];
        sml[p] = v > 0.f ? v : 0.f;
    }
    __syncthreads();

    for (int p = threadIdx.x; p < NLAB * 64; p += 256) {
        int i  = p >> 6;                 // output row (wave-uniform)
        int kk = p & 63;                 // output col within tile (= lane)
        const float* srow = &sS[i * NLAB];
        const float* mrow = &sml[kk * NLAB];
        float sum = 0.f;
        #pragma unroll
        for (int j = 0; j < NLAB; ++j) sum += srow[j] * mrow[j];
        out[(long)i * OUT_DIMS + k0 + kk] = sum;
    }
}

extern "C" void kernel_launch(void* const* d_in, const int* in_sizes, int n_in,
                              void* d_out, int out_size, void* d_ws, size_t ws_size,
                              hipStream_t stream) {
    const float* Label = (const float*)d_in[0];   // 63x8192
    const float* S     = (const float*)d_in[1];   // 63x63
    const float* W     = (const float*)d_in[2];   // 8192x8192
    const float* b     = (const float*)d_in[3];   // 8192
    float* out = (float*)d_out;

    unsigned short* A  = (unsigned short*)d_ws;                      // 1 MB bf16 A
    float*          Xp = (float*)((char*)d_ws + 64 * IN_DIMS * 2);   // 2 MB f32 partials

    // zero split-K accumulator (capture-safe)
    hipMemsetAsync(Xp, 0, (size_t)64 * OUT_DIMS * sizeof(float), stream);

    k_prep<<<dim3((64 * IN_DIMS / 4 + 255) / 256), dim3(256), 0, stream>>>(Label, A);
    k_gemm<<<dim3(128 * KS), dim3(256), 0, stream>>>(W, A, Xp);
    k_out <<<dim3(OUT_DIMS / 64), dim3(256), 0, stream>>>(Xp, S, b, out);
}